// Round 17
// baseline (92.944 us; speedup 1.0000x reference)
//
#include <hip/hip_runtime.h>
#include <hip/hip_fp16.h>
#include <math.h>

namespace {
constexpr int DIN = 36, DOUT = 34;
constexpr int TS = 5;                        // site tile 5x5x5 = 125 sites
constexpr int RT = 7;                        // staged rows per dim (5 + 2 halo)
constexpr int NROWS = RT*RT*RT;              // 343 rows
constexpr int ROWW  = 38;                    // dwords/row (36 data + 2 pad) = 152 B, odd 8B-bank stride
constexpr int NCHUNK = NROWS*9;              // 3087 16-B source chunks
constexpr int NTILE = 7;                     // tiles per dim, start = min(5t, 29)
constexpr int BLOCKS_PER_B = NTILE*NTILE*NTILE;  // 343
constexpr int NBLOCKS = 8*BLOCKS_PER_B;      // 2744 = 8 XCDs x 343
constexpr int NT = 512;                      // 4 w-groups x 128 site-slots
constexpr int SITER = (NCHUNK + NT - 1)/NT;  // 7
constexpr int D3 = DIN*DIN*DIN, D2 = DIN*DIN;
constexpr int WS_WPK  = 0;                   // 27 taps x 2 uint4 = 216 dwords
constexpr int WS_SCAL = 216;                 // br, bi, hb
constexpr int WS_HW   = 220;                 // 34 floats
}

__device__ __forceinline__ unsigned div9u(unsigned n) { return __umulhi(n, 0x38E38E39u) >> 1; }

__device__ __forceinline__ unsigned pack2h(float a, float b) {
    union { __half2 h; unsigned u; } x; x.h = __floats2half2_rn(a, b); return x.u;
}
__device__ __forceinline__ __half2 bch(unsigned u) {
    union { unsigned u; __half2 h; } x; x.u = u; return x.h;
}

// Packs weights into d_ws for scalar (uniform) loads in the main kernel.
__global__ void prep_kernel(const float* __restrict__ wr, const float* __restrict__ wi,
                            const float* __restrict__ br, const float* __restrict__ bi,
                            const float* __restrict__ hw, const float* __restrict__ hb,
                            unsigned* __restrict__ ws)
{
    const int t = threadIdx.x;
    if (t < 27) {
        uint4* p = reinterpret_cast<uint4*>(ws + WS_WPK);
        p[2*t]   = make_uint4(pack2h(wr[3*t],   -wi[3*t]),
                              pack2h(wr[3*t+1], -wi[3*t+1]),
                              pack2h(wr[3*t+2], -wi[3*t+2]), 0u);
        p[2*t+1] = make_uint4(pack2h(wi[3*t],    wr[3*t]),
                              pack2h(wi[3*t+1],  wr[3*t+1]),
                              pack2h(wi[3*t+2],  wr[3*t+2]), 0u);
    }
    if (t < DOUT) reinterpret_cast<float*>(ws)[WS_HW + t] = hw[t];
    if (t == 63) {
        float* s = reinterpret_cast<float*>(ws);
        s[WS_SCAL] = br[0]; s[WS_SCAL+1] = bi[0]; s[WS_SCAL+2] = hb[0];
    }
}

// Coalesced stage of both channels, interleaved (xr,xi) half2 per dword.
// Chunk C: row C/9 (7x7x7 region), 4 floats at chunk C%9.
// Small-range exact divides: /49 via *1338>>16 (n<=342), /7 via *9363>>16 (n<=48).
__device__ __forceinline__ void stage(const float* __restrict__ xr, const float* __restrict__ xi,
                                      unsigned* __restrict__ s_xu, int t, unsigned g0off)
{
    #pragma unroll
    for (int it = 0; it < SITER; ++it) {
        const int C = it*NT + t;
        if (C < NCHUNK) {
            const unsigned row = div9u((unsigned)C);
            const unsigned c   = (unsigned)C - row*9u;
            const unsigned rd  = (row*1338u) >> 16;
            const unsigned rem = row - rd*49u;
            const unsigned re  = (rem*9363u) >> 16;
            const unsigned rf  = rem - re*7u;
            const unsigned goff = g0off + rd*D3 + re*D2 + rf*DIN + c*4u;
            const float4 vr = *reinterpret_cast<const float4*>(xr + goff);
            const float4 vi = *reinterpret_cast<const float4*>(xi + goff);
            unsigned* dst = s_xu + row*ROWW + c*4;
            uint2 lo, hi;
            lo.x = pack2h(vr.x, vi.x); lo.y = pack2h(vr.y, vi.y);
            hi.x = pack2h(vr.z, vi.z); hi.y = pack2h(vr.w, vi.w);
            *reinterpret_cast<uint2*>(dst)     = lo;
            *reinterpret_cast<uint2*>(dst + 2) = hi;
        }
    }
}

// One w-group's conv + epilogue. Odd W0 handled by compile-time IDXOFF so all
// register indices stay static. Weights/head via uniform (scalar) loads.
template<int NW, int W0>
__device__ __forceinline__ float conv_group(const unsigned* __restrict__ s_xu,
                                            const uint4* __restrict__ wpk,
                                            const float* __restrict__ hws,
                                            int d, int e, int f,
                                            float c_br, float c_bi, float hinit)
{
    constexpr int BASE   = W0 & ~1;              // even dword -> 8B aligned reads
    constexpr int IDXOFF = W0 & 1;
    constexpr int NL = (IDXOFF + NW + 2 + 1)/2;  // b64 loads per row-window
    __half2 accr[NW], acci[NW];
    #pragma unroll
    for (int w = 0; w < NW; ++w) {
        accr[w] = __floats2half2_rn(0.f, 0.f);
        acci[w] = __floats2half2_rn(0.f, 0.f);
    }

    #pragma unroll 1
    for (int i = 0; i < 3; ++i)
    #pragma unroll 1
    for (int j = 0; j < 3; ++j)
    {
        // base row for k=0: (d+i, e+j, f); k shifts the row index by 1
        const unsigned* sp = s_xu + (((d+i)*RT + (e+j))*RT + f)*ROWW + BASE;
        const int tapb = (i*3 + j)*3;
        #pragma unroll
        for (int k = 0; k < 3; ++k)              // k*ROWW*4 folds into ds offsets
        {
            uint2 q[NL];
            #pragma unroll
            for (int m = 0; m < NL; ++m)
                q[m] = *reinterpret_cast<const uint2*>(sp + k*ROWW + 2*m);
            const __half2* win = reinterpret_cast<const __half2*>(q);

            const uint4 wa = wpk[2*(tapb + k)];      // uniform -> s_load, no LDS
            const uint4 wb = wpk[2*(tapb + k) + 1];
            #pragma unroll
            for (int l = 0; l < 3; ++l) {
                const __half2 WA = bch(l==0 ? wa.x : l==1 ? wa.y : wa.z);  // (wr,-wi)
                const __half2 WB = bch(l==0 ? wb.x : l==1 ? wb.y : wb.z);  // (wi, wr)
                #pragma unroll
                for (int w = 0; w < NW; ++w) {
                    const __half2 x2 = win[IDXOFF + w + l];     // (xr, xi), static idx
                    accr[w] = __hfma2(x2, WA, accr[w]);
                    acci[w] = __hfma2(x2, WB, acci[w]);
                }
            }
        }
    }

    // fp32 epilogue: sum halves -> bias -> CReLU -> modulus -> head partial
    float h = hinit;
    #pragma unroll
    for (int w = 0; w < NW; ++w) {
        const float yr = __low2float(accr[w]) + __high2float(accr[w]) + c_br;
        const float yi = __low2float(acci[w]) + __high2float(acci[w]) + c_bi;
        const float a = fmaxf(yr, 0.f);
        const float c = fmaxf(yi, 0.f);
        const float m = sqrtf(fmaf(a, a, fmaf(c, c, 1e-12f)));
        h = fmaf(m, hws[W0 + w], h);             // uniform index -> scalar load
    }
    return h;
}

__global__ __launch_bounds__(NT)
void lasl_kernel(const float* __restrict__ xr, const float* __restrict__ xi,
                 const unsigned* __restrict__ wsu, float* __restrict__ out)
{
    __shared__ unsigned s_xu[NROWS*ROWW];        // 52.1 KB -> 3 blocks/CU
    __shared__ float s_red[NT];

    const int t = threadIdx.x;

    // batch-per-XCD bijective swizzle: 2744 = 8 * 343
    const int bid = blockIdx.x;
    const int b   = bid & 7;
    int rem = bid >> 3;                          // 0..342
    const int dt = rem / 49;  rem -= dt*49;
    const int et = rem / 7;
    const int ft = rem - et*7;
    const int d0 = min(5*dt, 29);                // overlap tiles: duplicate outputs
    const int e0 = min(5*et, 29);                // write identical values
    const int f0 = min(5*ft, 29);

    const float* xrb = xr + (size_t)b * (size_t)(DIN*D3);
    const float* xib = xi + (size_t)b * (size_t)(DIN*D3);
    const unsigned g0off = (unsigned)((d0*DIN + e0)*DIN + f0)*DIN;

    stage(xrb, xib, s_xu, t, g0off);
    __syncthreads();

    const int s  = min(t & 127, 124);            // site slot (125 active, clamp keeps
    const int sv = (t & 127) < 125;              //  inactive lanes' LDS reads in-bounds)
    const int f  = s % 5;                        // site = (d,e,f) in 5x5x5
    const int e  = (s / 5) % 5;
    const int d  = s / 25;
    const int g  = t >> 7;                       // wave-uniform w-group (4 groups)

    const uint4* wpk  = reinterpret_cast<const uint4*>(wsu + WS_WPK);
    const float* scal = reinterpret_cast<const float*>(wsu);
    const float* hws  = scal + WS_HW;
    const float c_br = scal[WS_SCAL], c_bi = scal[WS_SCAL+1];
    const float hini = (g == 0) ? scal[WS_SCAL+2] : 0.f;   // hb counted once

    // w-groups {9,8,9,8} at W0 {0,9,17,26}
    float hp;
    if      (g == 0) hp = conv_group<9, 0>(s_xu, wpk, hws, d, e, f, c_br, c_bi, hini);
    else if (g == 1) hp = conv_group<8, 9>(s_xu, wpk, hws, d, e, f, c_br, c_bi, hini);
    else if (g == 2) hp = conv_group<9,17>(s_xu, wpk, hws, d, e, f, c_br, c_bi, hini);
    else             hp = conv_group<8,26>(s_xu, wpk, hws, d, e, f, c_br, c_bi, hini);

    // combine the 4 w-group partials through LDS (single barrier: write -> read)
    s_red[t] = hp;
    __syncthreads();

    if (g == 0 && sv) {
        const float htot = hp + s_red[t + 128] + s_red[t + 256] + s_red[t + 384];
        out[(((size_t)b*DOUT + (d0 + d))*DOUT + (e0 + e))*DOUT + (f0 + f)] =
            1.f / (1.f + __expf(-htot));
    }
}

extern "C" void kernel_launch(void* const* d_in, const int* in_sizes, int n_in,
                              void* d_out, int out_size, void* d_ws, size_t ws_size,
                              hipStream_t stream)
{
    const float* xr = (const float*)d_in[0];
    const float* xi = (const float*)d_in[1];
    const float* wr = (const float*)d_in[2];
    const float* wi = (const float*)d_in[3];
    const float* br = (const float*)d_in[4];
    const float* bi = (const float*)d_in[5];
    const float* hw = (const float*)d_in[6];
    const float* hb = (const float*)d_in[7];
    float* out = (float*)d_out;
    unsigned* ws = (unsigned*)d_ws;

    prep_kernel<<<1, 64, 0, stream>>>(wr, wi, br, bi, hw, hb, ws);
    lasl_kernel<<<NBLOCKS, NT, 0, stream>>>(xr, xi, ws, out);
}

// Round 18
// 90.713 us; speedup vs baseline: 1.0246x; 1.0246x over previous
//
#include <hip/hip_runtime.h>
#include <hip/hip_fp16.h>
#include <math.h>

namespace {
constexpr int DIN = 36, DOUT = 34;
constexpr int RT = 6;                        // staged rows per dim (4 sites + 2 halo)
constexpr int NROWS = RT*RT*RT;              // 216 rows
constexpr int ROWW  = 38;                    // dwords/row (36 data + 2 pad) = 152 B
constexpr int NCHUNK = NROWS*9;              // 1944 16-B source chunks
constexpr int NTILE = 9;                     // tiles per dim, start = min(4t, 30)
constexpr int BLOCKS_PER_B = NTILE*NTILE*NTILE;  // 729
constexpr int NBLOCKS = 8*BLOCKS_PER_B;      // 5832 = 8 XCDs x 729
constexpr int NT = 512;                      // 8 waves: wave g = w-group, lane = site
constexpr int SITER = (NCHUNK + NT - 1)/NT;  // 4
constexpr int D3 = DIN*DIN*DIN, D2 = DIN*DIN;
constexpr int WS_WPK  = 0;                   // 27 taps x 2 uint4 = 216 dwords
constexpr int WS_SCAL = 216;                 // br, bi, hb
constexpr int WS_HW   = 220;                 // 34 floats
}

__device__ __forceinline__ unsigned div9u(unsigned n) { return __umulhi(n, 0x38E38E39u) >> 1; }
__device__ __forceinline__ unsigned div6u(unsigned n) { return __umulhi(n, 0xAAAAAAABu) >> 2; }

__device__ __forceinline__ unsigned pack2h(float a, float b) {
    union { __half2 h; unsigned u; } x; x.h = __floats2half2_rn(a, b); return x.u;
}
__device__ __forceinline__ __half2 bch(unsigned u) {
    union { unsigned u; __half2 h; } x; x.u = u; return x.h;
}

// Packs weights into d_ws for scalar (uniform) loads in the main kernel.
__global__ void prep_kernel(const float* __restrict__ wr, const float* __restrict__ wi,
                            const float* __restrict__ br, const float* __restrict__ bi,
                            const float* __restrict__ hw, const float* __restrict__ hb,
                            unsigned* __restrict__ ws)
{
    const int t = threadIdx.x;
    if (t < 27) {
        uint4* p = reinterpret_cast<uint4*>(ws + WS_WPK);
        p[2*t]   = make_uint4(pack2h(wr[3*t],   -wi[3*t]),
                              pack2h(wr[3*t+1], -wi[3*t+1]),
                              pack2h(wr[3*t+2], -wi[3*t+2]), 0u);
        p[2*t+1] = make_uint4(pack2h(wi[3*t],    wr[3*t]),
                              pack2h(wi[3*t+1],  wr[3*t+1]),
                              pack2h(wi[3*t+2],  wr[3*t+2]), 0u);
    }
    if (t < DOUT) reinterpret_cast<float*>(ws)[WS_HW + t] = hw[t];
    if (t == 63) {
        float* s = reinterpret_cast<float*>(ws);
        s[WS_SCAL] = br[0]; s[WS_SCAL+1] = bi[0]; s[WS_SCAL+2] = hb[0];
    }
}

// Coalesced stage of both channels, interleaved (xr,xi) half2 per dword.
// Chunk C: row C/9 (6x6x6 region), 4 floats at chunk C%9.
__device__ __forceinline__ void stage(const float* __restrict__ xr, const float* __restrict__ xi,
                                      unsigned* __restrict__ s_xu, int t, unsigned g0off)
{
    #pragma unroll
    for (int it = 0; it < SITER; ++it) {
        const int C = it*NT + t;
        if (C < NCHUNK) {
            const unsigned row = div9u((unsigned)C);
            const unsigned c   = (unsigned)C - row*9u;
            const unsigned rd  = div9u(row) >> 2;        // row / 36
            const unsigned rem = row - rd*36u;
            const unsigned re  = div6u(rem);
            const unsigned rf  = rem - re*6u;
            const unsigned goff = g0off + rd*D3 + re*D2 + rf*DIN + c*4u;
            const float4 vr = *reinterpret_cast<const float4*>(xr + goff);
            const float4 vi = *reinterpret_cast<const float4*>(xi + goff);
            unsigned* dst = s_xu + row*ROWW + c*4;
            uint2 lo, hi;
            lo.x = pack2h(vr.x, vi.x); lo.y = pack2h(vr.y, vi.y);
            hi.x = pack2h(vr.z, vi.z); hi.y = pack2h(vr.w, vi.w);
            *reinterpret_cast<uint2*>(dst)     = lo;
            *reinterpret_cast<uint2*>(dst + 2) = hi;
        }
    }
}

// One w-group's conv + epilogue. Weights/head via uniform (scalar) loads.
// All register indices compile-time (no scratch demotion).
template<int NW, int W0>
__device__ __forceinline__ float conv_group(const unsigned* __restrict__ s_xu,
                                            const uint4* __restrict__ wpk,
                                            const float* __restrict__ hws,
                                            int d, int e, int f,
                                            float c_br, float c_bi, float hinit)
{
    constexpr int NL = (NW + 2)/2;               // b64 loads per row-window
    __half2 accr[NW], acci[NW];
    #pragma unroll
    for (int w = 0; w < NW; ++w) {
        accr[w] = __floats2half2_rn(0.f, 0.f);
        acci[w] = __floats2half2_rn(0.f, 0.f);
    }

    #pragma unroll 1
    for (int i = 0; i < 3; ++i)
    #pragma unroll 1
    for (int j = 0; j < 3; ++j)
    {
        // base row for k=0: (d+i, e+j, f); k shifts the row index by 1
        const unsigned* sp = s_xu + (((d+i)*RT + (e+j))*RT + f)*ROWW + W0;
        const int tapb = (i*3 + j)*3;
        #pragma unroll
        for (int k = 0; k < 3; ++k)              // k*ROWW*4 folds into ds offsets
        {
            uint2 q[NL];
            #pragma unroll
            for (int m = 0; m < NL; ++m)
                q[m] = *reinterpret_cast<const uint2*>(sp + k*ROWW + 2*m);
            const __half2* win = reinterpret_cast<const __half2*>(q);

            const uint4 wa = wpk[2*(tapb + k)];      // uniform -> s_load, no LDS
            const uint4 wb = wpk[2*(tapb + k) + 1];
            #pragma unroll
            for (int l = 0; l < 3; ++l) {
                const __half2 WA = bch(l==0 ? wa.x : l==1 ? wa.y : wa.z);  // (wr,-wi)
                const __half2 WB = bch(l==0 ? wb.x : l==1 ? wb.y : wb.z);  // (wi, wr)
                #pragma unroll
                for (int w = 0; w < NW; ++w) {
                    const __half2 x2 = win[w + l];          // (xr, xi)
                    accr[w] = __hfma2(x2, WA, accr[w]);
                    acci[w] = __hfma2(x2, WB, acci[w]);
                }
            }
        }
    }

    // fp32 epilogue: sum halves -> bias -> CReLU -> modulus -> head partial
    float h = hinit;
    #pragma unroll
    for (int w = 0; w < NW; ++w) {
        const float yr = __low2float(accr[w]) + __high2float(accr[w]) + c_br;
        const float yi = __low2float(acci[w]) + __high2float(acci[w]) + c_bi;
        const float a = fmaxf(yr, 0.f);
        const float c = fmaxf(yi, 0.f);
        const float m = sqrtf(fmaf(a, a, fmaf(c, c, 1e-12f)));
        h = fmaf(m, hws[W0 + w], h);             // uniform index -> scalar load
    }
    return h;
}

__global__ __launch_bounds__(NT)
void lasl_kernel(const float* __restrict__ xr, const float* __restrict__ xi,
                 const unsigned* __restrict__ wsu, float* __restrict__ out)
{
    __shared__ unsigned s_xu[NROWS*ROWW];        // 32.8 KB -> 4 blocks/CU
    __shared__ float s_red[NT];

    const int t = threadIdx.x;

    // batch-per-XCD bijective swizzle: 5832 = 8 * 729
    const int bid = blockIdx.x;
    const int b   = bid & 7;
    int rem = bid >> 3;                          // 0..728
    const int dt = rem / 81;  rem -= dt*81;
    const int et = rem / 9;
    const int ft = rem - (rem/9)*9;
    const int d0 = min(4*dt, 30);                // overlap tiles: duplicate outputs
    const int e0 = min(4*et, 30);                // write identical values
    const int f0 = min(4*ft, 30);

    const float* xrb = xr + (size_t)b * (size_t)(DIN*D3);
    const float* xib = xi + (size_t)b * (size_t)(DIN*D3);
    const unsigned g0off = (unsigned)((d0*DIN + e0)*DIN + f0)*DIN;

    stage(xrb, xib, s_xu, t, g0off);
    __syncthreads();

    const int f = t & 3;                         // lane = site (4x4x4)
    const int e = (t >> 2) & 3;
    const int d = (t >> 4) & 3;
    const int g = t >> 6;                        // wave-uniform w-group (8 waves)

    const uint4* wpk  = reinterpret_cast<const uint4*>(wsu + WS_WPK);
    const float* scal = reinterpret_cast<const float*>(wsu);
    const float* hws  = scal + WS_HW;
    const float c_br = scal[WS_SCAL], c_bi = scal[WS_SCAL+1];
    const float hini = (g == 0) ? scal[WS_SCAL+2] : 0.f;   // hb counted once

    float hp;
    if      (g == 0) hp = conv_group<6, 0>(s_xu, wpk, hws, d, e, f, c_br, c_bi, hini);
    else if (g == 1) hp = conv_group<4, 6>(s_xu, wpk, hws, d, e, f, c_br, c_bi, hini);
    else if (g == 2) hp = conv_group<4,10>(s_xu, wpk, hws, d, e, f, c_br, c_bi, hini);
    else if (g == 3) hp = conv_group<4,14>(s_xu, wpk, hws, d, e, f, c_br, c_bi, hini);
    else if (g == 4) hp = conv_group<4,18>(s_xu, wpk, hws, d, e, f, c_br, c_bi, hini);
    else if (g == 5) hp = conv_group<4,22>(s_xu, wpk, hws, d, e, f, c_br, c_bi, hini);
    else if (g == 6) hp = conv_group<4,26>(s_xu, wpk, hws, d, e, f, c_br, c_bi, hini);
    else             hp = conv_group<4,30>(s_xu, wpk, hws, d, e, f, c_br, c_bi, hini);

    // combine the 8 w-group partials (one per wave) through LDS
    __syncthreads();                             // all s_xu reads done
    s_red[t] = hp;
    __syncthreads();

    if (g == 0) {
        float htot = hp;
        #pragma unroll
        for (int gg = 1; gg < 8; ++gg) htot += s_red[t + 64*gg];
        out[(((size_t)b*DOUT + (d0 + d))*DOUT + (e0 + e))*DOUT + (f0 + f)] =
            1.f / (1.f + __expf(-htot));
    }
}

extern "C" void kernel_launch(void* const* d_in, const int* in_sizes, int n_in,
                              void* d_out, int out_size, void* d_ws, size_t ws_size,
                              hipStream_t stream)
{
    const float* xr = (const float*)d_in[0];
    const float* xi = (const float*)d_in[1];
    const float* wr = (const float*)d_in[2];
    const float* wi = (const float*)d_in[3];
    const float* br = (const float*)d_in[4];
    const float* bi = (const float*)d_in[5];
    const float* hw = (const float*)d_in[6];
    const float* hb = (const float*)d_in[7];
    float* out = (float*)d_out;
    unsigned* ws = (unsigned*)d_ws;

    prep_kernel<<<1, 64, 0, stream>>>(wr, wi, br, bi, hw, hb, ws);
    lasl_kernel<<<NBLOCKS, NT, 0, stream>>>(xr, xi, ws, out);
}